// Round 7
// baseline (479.050 us; speedup 1.0000x reference)
//
#include <hip/hip_runtime.h>

typedef _Float16 f16;
typedef _Float16 f16x8 __attribute__((ext_vector_type(8)));
typedef float f32x4 __attribute__((ext_vector_type(4)));

#define N_ATOMS 50000
#define NEIGH   12
#define NEDGE   (N_ATOMS * NEIGH)
#define NCRYS   500
#define NBLK    196  // ceil(50000/256)

// ---------------- input transpose: in[N][C] -> out[C][N] ----------------
template <int C>
__global__ __launch_bounds__(256) void transposeT(const float* __restrict__ in,
                                                  float* __restrict__ outp) {
  __shared__ float tile[64 * C];
  const int r0 = blockIdx.x * 64;
  const int nr = min(64, N_ATOMS - r0);
  for (int idx = threadIdx.x; idx < nr * C; idx += 256) {
    int r = idx / C, c = idx - r * C;
    tile[r * C + c] = in[(size_t)(r0 + r) * C + c];
  }
  __syncthreads();
  for (int idx = threadIdx.x; idx < 64 * C; idx += 256) {
    int c = idx >> 6, r = idx & 63;
    if (r < nr) outp[(size_t)c * N_ATOMS + r0 + r] = tile[r * C + c];
  }
}

// ---------------- layer-1 register GEMM (no LDS, no barriers) ----------------
// Per model t ~ LDS-staged-bytes/4.24TB/s (R3/R5/R6 fit): drop LDS entirely.
// Block 256thr = 4 waves (2wr x 2wc), covers 128 rows x 128 cols of half
// blockIdx.y (0 -> Wl/P, 1 -> Wr/Q). B-frags loaded direct from L2-hot W;
// A-frags = GBF computed in-register from transposed input (coalesced d-loads).
// MODE 1: bondT [12][N], K=480 (40 filters). MODE 2: angleT [144][N], K=1152.
template <int MODE, int K>
__global__ __launch_bounds__(256) void gemm1_reg(
    const float* __restrict__ AT, const f16* __restrict__ Wcat,
    f16* __restrict__ P, f16* __restrict__ Q, int n) {
  const int lane = threadIdx.x & 63;
  const int wid = threadIdx.x >> 6;
  const int wr = wid & 1;
  const int wc = wid >> 1;
  const int row0 = blockIdx.x * 128;
  const f16* Wh = Wcat + (size_t)blockIdx.y * 128 * K;
  f16* outp = blockIdx.y ? Q : P;
  const int r16 = lane & 15;
  const int kb = lane >> 4;

  int rm[4];
#pragma unroll
  for (int m = 0; m < 4; ++m) {
    int r = row0 + wr * 64 + m * 16 + r16;
    rm[m] = (r < n) ? r : (n - 1);
  }
  const f16* wb[4];
#pragma unroll
  for (int q = 0; q < 4; ++q)
    wb[q] = Wh + (size_t)(wc * 64 + q * 16 + r16) * K + kb * 8;

  f32x4 acc[4][4];
#pragma unroll
  for (int m = 0; m < 4; ++m)
#pragma unroll
    for (int q = 0; q < 4; ++q) acc[m][q] = (f32x4)0.f;

  constexpr int NT = K / 32;
  // prefetch t=0
  float d0[4];
  f16x8 b0[4];
  {
    int kg = kb * 8;
    int jn = (MODE == 1) ? kg / 40 : (kg >> 3);
#pragma unroll
    for (int m = 0; m < 4; ++m) d0[m] = AT[(size_t)jn * N_ATOMS + rm[m]];
#pragma unroll
    for (int q = 0; q < 4; ++q) b0[q] = *(const f16x8*)(wb[q]);
  }

  for (int t = 0; t < NT; ++t) {
    float d1[4];
    f16x8 b1[4];
    if (t + 1 < NT) {  // issue next-tile loads before this tile's compute
      int kg = (t + 1) * 32 + kb * 8;
      int jn = (MODE == 1) ? kg / 40 : (kg >> 3);
#pragma unroll
      for (int m = 0; m < 4; ++m) d1[m] = AT[(size_t)jn * N_ATOMS + rm[m]];
#pragma unroll
      for (int q = 0; q < 4; ++q) b1[q] = *(const f16x8*)(wb[q] + (t + 1) * 32);
    }
    // A-frags: 8 GBF values from one d each (8-run never crosses a group:
    // MODE1 40%8==0, MODE2 groups are exactly 8 wide)
    f16x8 a[4];
    float fbase, fstep, g2i;
    if constexpr (MODE == 1) {
      int kg = t * 32 + kb * 8;
      int jn = kg / 40;
      fbase = (float)(kg - jn * 40) * (8.0f / 39.0f);
      fstep = 8.0f / 39.0f;
      g2i = 25.0f;
    } else {
      fbase = -1.0f;
      fstep = 2.0f / 7.0f;
      g2i = 16.0f;
    }
#pragma unroll
    for (int m = 0; m < 4; ++m) {
      float dd = d0[m];
#pragma unroll
      for (int j = 0; j < 8; ++j) {
        float tt = dd - (fbase + (float)j * fstep);
        a[m][j] = (f16)__expf(-tt * tt * g2i);
      }
    }
#pragma unroll
    for (int m = 0; m < 4; ++m)
#pragma unroll
      for (int q = 0; q < 4; ++q)
        acc[m][q] =
            __builtin_amdgcn_mfma_f32_16x16x32_f16(a[m], b0[q], acc[m][q], 0, 0, 0);
#pragma unroll
    for (int m = 0; m < 4; ++m) d0[m] = d1[m];
#pragma unroll
    for (int q = 0; q < 4; ++q) b0[q] = b1[q];
  }

  const int crow = (lane >> 4) * 4;
  const int ccol = lane & 15;
#pragma unroll
  for (int m = 0; m < 4; ++m) {
#pragma unroll
    for (int r = 0; r < 4; ++r) {
      int row = row0 + wr * 64 + m * 16 + crow + r;
      if (row < n) {
#pragma unroll
        for (int q = 0; q < 4; ++q)
          outp[(size_t)row * 128 + wc * 64 + q * 16 + ccol] = (f16)acc[m][q][r];
      }
    }
  }
}

// ---------------- layers 2-3 register GEMM: dst.x = relu([agg|x]@W^T + b) ----
// Reads src[N][256] (agg|x), writes x-half of dst (ping-pong: no-barrier safe).
__global__ __launch_bounds__(256) void gemmL_reg(
    const f16* __restrict__ srcB, const f16* __restrict__ srcA,
    f16* __restrict__ dstB, f16* __restrict__ dstA, const f16* __restrict__ Wall,
    const float* __restrict__ bb, const float* __restrict__ ba, int lidx, int n) {
  const int path = blockIdx.y;
  const f16* src = path ? srcA : srcB;
  f16* dst = path ? dstA : dstB;
  const f16* W = Wall + (size_t)(path * 2 + lidx) * 32768;
  const float* bias = (path ? ba : bb) + lidx * 128;

  const int lane = threadIdx.x & 63;
  const int wid = threadIdx.x >> 6;
  const int wr = wid & 1;
  const int wc = wid >> 1;
  const int row0 = blockIdx.x * 128;
  const int r16 = lane & 15;
  const int kb = lane >> 4;

  int rm[4];
#pragma unroll
  for (int m = 0; m < 4; ++m) {
    int r = row0 + wr * 64 + m * 16 + r16;
    rm[m] = (r < n) ? r : (n - 1);
  }
  const f16* wb[4];
#pragma unroll
  for (int q = 0; q < 4; ++q)
    wb[q] = W + (size_t)(wc * 64 + q * 16 + r16) * 256 + kb * 8;

  f32x4 acc[4][4];
#pragma unroll
  for (int m = 0; m < 4; ++m)
#pragma unroll
    for (int q = 0; q < 4; ++q) acc[m][q] = (f32x4)0.f;

  f16x8 a0[4], b0[4];
#pragma unroll
  for (int m = 0; m < 4; ++m)
    a0[m] = *(const f16x8*)&src[(size_t)rm[m] * 256 + kb * 8];
#pragma unroll
  for (int q = 0; q < 4; ++q) b0[q] = *(const f16x8*)(wb[q]);

  for (int t = 0; t < 8; ++t) {
    f16x8 a1[4], b1[4];
    if (t + 1 < 8) {
      int k = (t + 1) * 32 + kb * 8;
#pragma unroll
      for (int m = 0; m < 4; ++m)
        a1[m] = *(const f16x8*)&src[(size_t)rm[m] * 256 + k];
#pragma unroll
      for (int q = 0; q < 4; ++q) b1[q] = *(const f16x8*)(wb[q] + (t + 1) * 32);
    }
#pragma unroll
    for (int m = 0; m < 4; ++m)
#pragma unroll
      for (int q = 0; q < 4; ++q)
        acc[m][q] =
            __builtin_amdgcn_mfma_f32_16x16x32_f16(a0[m], b0[q], acc[m][q], 0, 0, 0);
#pragma unroll
    for (int m = 0; m < 4; ++m) a0[m] = a1[m];
#pragma unroll
    for (int q = 0; q < 4; ++q) b0[q] = b1[q];
  }

  const int crow = (lane >> 4) * 4;
  const int ccol = lane & 15;
#pragma unroll
  for (int m = 0; m < 4; ++m) {
#pragma unroll
    for (int r = 0; r < 4; ++r) {
      int row = row0 + wr * 64 + m * 16 + crow + r;
      if (row < n) {
#pragma unroll
        for (int q = 0; q < 4; ++q) {
          int col = wc * 64 + q * 16 + ccol;
          float v = acc[m][q][r] + bias[col];
          dst[(size_t)row * 256 + 128 + col] = (f16)fmaxf(v, 0.0f);
        }
      }
    }
  }
}

// ---------------- weight conversion ----------------
__global__ void cvtW(const float* __restrict__ Wl, const float* __restrict__ Wr,
                     f16* __restrict__ outp, int K) {
  int c = blockIdx.y;
  int k = blockIdx.x * 256 + threadIdx.x;
  if (k < K)
    outp[(size_t)c * K + k] =
        (f16)((c < 128) ? Wl[(size_t)c * K + k] : Wr[(size_t)(c - 128) * K + k]);
}

// [4][128][256]: l = {b0,b1,a0,a1}; k<128 -> Wl, k>=128 -> Wr
__global__ void cvtW_small(const float* __restrict__ Wl_b, const float* __restrict__ Wr_b,
                           const float* __restrict__ Wl_a, const float* __restrict__ Wr_a,
                           f16* __restrict__ outp) {
  int idx = blockIdx.x * 256 + threadIdx.x;  // 4*128*256 = 131072
  int l = idx >> 15;
  int c = (idx >> 8) & 127;
  int k = idx & 255;
  const float* Wl = (l < 2) ? Wl_b + (size_t)l * 16384 : Wl_a + (size_t)(l - 2) * 16384;
  const float* Wr = (l < 2) ? Wr_b + (size_t)l * 16384 : Wr_a + (size_t)(l - 2) * 16384;
  float v = (k < 128) ? Wl[(size_t)c * 128 + k] : Wr[(size_t)c * 128 + (k - 128)];
  outp[idx] = (f16)v;
}

// ---------------- CSR build ----------------
__global__ void k_count(const int* __restrict__ nbr, int* __restrict__ deg) {
  int e = blockIdx.x * 256 + threadIdx.x;
  if (e < NEDGE) atomicAdd(&deg[nbr[e]], 1);
}
__global__ void k_scan1(const int* __restrict__ deg, int* __restrict__ rowptr,
                        int* __restrict__ bsum) {
  __shared__ int s[256];
  int t = threadIdx.x, i = blockIdx.x * 256 + t;
  int v = (i < N_ATOMS) ? deg[i] : 0;
  s[t] = v;
  __syncthreads();
  for (int off = 1; off < 256; off <<= 1) {
    int x = (t >= off) ? s[t - off] : 0;
    __syncthreads();
    s[t] += x;
    __syncthreads();
  }
  if (i < N_ATOMS) rowptr[i] = s[t] - v;
  if (t == 255) bsum[blockIdx.x] = s[255];
}
__global__ void k_scan2(int* __restrict__ bsum) {
  __shared__ int s[256];
  int t = threadIdx.x;
  int v = (t < NBLK) ? bsum[t] : 0;
  s[t] = v;
  __syncthreads();
  for (int off = 1; off < 256; off <<= 1) {
    int x = (t >= off) ? s[t - off] : 0;
    __syncthreads();
    s[t] += x;
    __syncthreads();
  }
  if (t < NBLK) bsum[t] = s[t] - v;
}
__global__ void k_scan3(int* __restrict__ rowptr, const int* __restrict__ bsum) {
  int i = blockIdx.x * 256 + threadIdx.x;
  if (i < N_ATOMS) rowptr[i] += bsum[blockIdx.x];
  if (i == 0) rowptr[N_ATOMS] = NEDGE;
}
__global__ void k_fill(const int* __restrict__ nbr, const int* __restrict__ rowptr,
                       int* __restrict__ cursor, int* __restrict__ eidx) {
  int e = blockIdx.x * 256 + threadIdx.x;
  if (e < NEDGE) {
    int dst = nbr[e];
    int pos = rowptr[dst] + atomicAdd(&cursor[dst], 1);
    eidx[pos] = e / NEIGH;
  }
}

// ---------------- layer-1 finalize: x = relu(mean_j P[src_j] + b + Q) ----------------
__global__ __launch_bounds__(256) void gather_fin1(
    const f16* __restrict__ Pb, const f16* __restrict__ Qb,
    const f16* __restrict__ Pa, const f16* __restrict__ Qa,
    const int* __restrict__ rowptr, const int* __restrict__ eidx,
    const float* __restrict__ bias_b, const float* __restrict__ bias_a,
    f16* __restrict__ axb, f16* __restrict__ axa) {
  const int path = blockIdx.y;
  const f16* P = path ? Pa : Pb;
  const f16* Q = path ? Qa : Qb;
  const float* bias = path ? bias_a : bias_b;
  f16* ax = path ? axa : axb;
  const int t = threadIdx.x;
  const int a = blockIdx.x * 16 + (t >> 4);
  const int g = (t & 15) * 8;
  const int s0 = rowptr[a], s1 = rowptr[a + 1];
  float acc[8];
#pragma unroll
  for (int u = 0; u < 8; ++u) acc[u] = 0.f;
  int j = s0;
  for (; j + 4 <= s1; j += 4) {
    int src0 = eidx[j], src1 = eidx[j + 1], src2 = eidx[j + 2], src3 = eidx[j + 3];
    f16x8 v0 = *(const f16x8*)&P[(size_t)src0 * 128 + g];
    f16x8 v1 = *(const f16x8*)&P[(size_t)src1 * 128 + g];
    f16x8 v2 = *(const f16x8*)&P[(size_t)src2 * 128 + g];
    f16x8 v3 = *(const f16x8*)&P[(size_t)src3 * 128 + g];
#pragma unroll
    for (int u = 0; u < 8; ++u)
      acc[u] += ((float)v0[u] + (float)v1[u]) + ((float)v2[u] + (float)v3[u]);
  }
  for (; j < s1; ++j) {
    f16x8 v = *(const f16x8*)&P[(size_t)eidx[j] * 128 + g];
#pragma unroll
    for (int u = 0; u < 8; ++u) acc[u] += (float)v[u];
  }
  f16x8 q = *(const f16x8*)&Q[(size_t)a * 128 + g];
  float inv = 1.0f / fmaxf((float)(s1 - s0), 1.0f);
  f16 outv[8];
#pragma unroll
  for (int u = 0; u < 8; ++u) {
    float v = acc[u] * inv + bias[g + u] + (float)q[u];
    outv[u] = (f16)fmaxf(v, 0.0f);
  }
  *(f16x8*)&ax[(size_t)a * 256 + 128 + g] = *(const f16x8*)outv;
}

// ---------------- layers 2-3 aggregation: agg half <- mean_j x[src_j] ----------------
__global__ __launch_bounds__(256) void gather_mean(
    f16* __restrict__ axb, f16* __restrict__ axa,
    const int* __restrict__ rowptr, const int* __restrict__ eidx) {
  f16* ax = blockIdx.y ? axa : axb;
  const int t = threadIdx.x;
  const int a = blockIdx.x * 16 + (t >> 4);
  const int g = (t & 15) * 8;
  const int s0 = rowptr[a], s1 = rowptr[a + 1];
  float acc[8];
#pragma unroll
  for (int u = 0; u < 8; ++u) acc[u] = 0.f;
  int j = s0;
  for (; j + 4 <= s1; j += 4) {
    int src0 = eidx[j], src1 = eidx[j + 1], src2 = eidx[j + 2], src3 = eidx[j + 3];
    f16x8 v0 = *(const f16x8*)&ax[(size_t)src0 * 256 + 128 + g];
    f16x8 v1 = *(const f16x8*)&ax[(size_t)src1 * 256 + 128 + g];
    f16x8 v2 = *(const f16x8*)&ax[(size_t)src2 * 256 + 128 + g];
    f16x8 v3 = *(const f16x8*)&ax[(size_t)src3 * 256 + 128 + g];
#pragma unroll
    for (int u = 0; u < 8; ++u)
      acc[u] += ((float)v0[u] + (float)v1[u]) + ((float)v2[u] + (float)v3[u]);
  }
  for (; j < s1; ++j) {
    f16x8 v = *(const f16x8*)&ax[(size_t)eidx[j] * 256 + 128 + g];
#pragma unroll
    for (int u = 0; u < 8; ++u) acc[u] += (float)v[u];
  }
  float inv = 1.0f / fmaxf((float)(s1 - s0), 1.0f);
  f16 outv[8];
#pragma unroll
  for (int u = 0; u < 8; ++u) outv[u] = (f16)(acc[u] * inv);
  *(f16x8*)&ax[(size_t)a * 256 + g] = *(const f16x8*)outv;
}

// ---------------- head: pool -> mlp -> mlp -> fc ----------------
__global__ __launch_bounds__(256) void head_kernel(
    const f16* __restrict__ axb, const f16* __restrict__ axa,
    const int* __restrict__ crys, const float* __restrict__ W_mlp,
    const float* __restrict__ b_mlp, const float* __restrict__ W_fc,
    const float* __restrict__ b_fc, float* __restrict__ outp) {
  __shared__ float sh0[256], sh1[256];
  const int cry = blockIdx.x, c = threadIdx.x;
  const int s = crys[2 * cry], e = crys[2 * cry + 1];
  const f16* src = (c < 128) ? axb : axa;
  const int ch = c & 127;
  float sum = 0.f;
  for (int r = s; r < e; ++r) sum += (float)src[(size_t)r * 256 + 128 + ch];
  sh0[c] = sum / fmaxf((float)(e - s), 1.0f);
  __syncthreads();
  {
    const float* wrow = W_mlp + (size_t)c * 256;
    float s2 = b_mlp[c];
#pragma unroll 8
    for (int k = 0; k < 256; k += 4) {
      float4 w = *(const float4*)&wrow[k];
      s2 += sh0[k] * w.x + sh0[k + 1] * w.y + sh0[k + 2] * w.z + sh0[k + 3] * w.w;
    }
    sh1[c] = s2;
  }
  __syncthreads();
  {
    const float* wrow = W_mlp + 65536 + (size_t)c * 256;
    float s2 = b_mlp[256 + c];
#pragma unroll 8
    for (int k = 0; k < 256; k += 4) {
      float4 w = *(const float4*)&wrow[k];
      s2 += sh1[k] * w.x + sh1[k + 1] * w.y + sh1[k + 2] * w.z + sh1[k + 3] * w.w;
    }
    sh0[c] = s2;
  }
  __syncthreads();
  if (c < 2) {
    const float* wrow = W_fc + c * 256;
    float s2 = b_fc[c];
    for (int k = 0; k < 256; ++k) s2 += sh0[k] * wrow[k];
    outp[cry * 2 + c] = s2;
  }
}

extern "C" void kernel_launch(void* const* d_in, const int* in_sizes, int n_in,
                              void* d_out, int out_size, void* d_ws, size_t ws_size,
                              hipStream_t stream) {
  const float* bond  = (const float*)d_in[0];
  const float* angle = (const float*)d_in[1];
  const int*   nbr   = (const int*)d_in[3];
  const int*   crys  = (const int*)d_in[4];
  const float* Wl_b1 = (const float*)d_in[5];
  const float* Wr_b1 = (const float*)d_in[6];
  const float* b_b1  = (const float*)d_in[7];
  const float* Wl_a1 = (const float*)d_in[8];
  const float* Wr_a1 = (const float*)d_in[9];
  const float* b_a1  = (const float*)d_in[10];
  const float* Wl_b  = (const float*)d_in[11];
  const float* Wr_b  = (const float*)d_in[12];
  const float* b_b   = (const float*)d_in[13];
  const float* Wl_a  = (const float*)d_in[14];
  const float* Wr_a  = (const float*)d_in[15];
  const float* b_a   = (const float*)d_in[16];
  const float* W_mlp = (const float*)d_in[17];
  const float* b_mlp = (const float*)d_in[18];
  const float* W_fc  = (const float*)d_in[19];
  const float* b_fc  = (const float*)d_in[20];

  char* w = (char*)d_ws;
  auto alloc = [&](size_t bytes) {
    void* p = (void*)w;
    w += (bytes + 255) & ~(size_t)255;
    return p;
  };
  // ping-pong activation buffers; P/Q for layer 1 alias the B buffers
  f16* axbA = (f16*)alloc((size_t)N_ATOMS * 256 * 2);
  f16* axaA = (f16*)alloc((size_t)N_ATOMS * 256 * 2);
  f16* axbB = (f16*)alloc((size_t)N_ATOMS * 256 * 2);
  f16* axaB = (f16*)alloc((size_t)N_ATOMS * 256 * 2);
  f16* Pb = axbB;
  f16* Qb = axbB + (size_t)N_ATOMS * 128;
  f16* Pa = axaB;
  f16* Qa = axaB + (size_t)N_ATOMS * 128;
  float* angleT = (float*)alloc((size_t)144 * N_ATOMS * 4);
  float* bondT  = (float*)alloc((size_t)12 * N_ATOMS * 4);
  f16* Wb1c = (f16*)alloc((size_t)256 * 480 * 2);
  f16* Wa1c = (f16*)alloc((size_t)256 * 1152 * 2);
  f16* Wsm  = (f16*)alloc((size_t)4 * 128 * 256 * 2);
  // deg+cursor as ONE contiguous block: the single memset must cover BOTH
  // (0xAA re-poison between timed replays otherwise leaves cursor garbage).
  int* deg    = (int*)alloc((size_t)2 * N_ATOMS * 4);
  int* cursor = deg + N_ATOMS;
  int* rowptr = (int*)alloc((size_t)(N_ATOMS + 1) * 4);
  int* eidx   = (int*)alloc((size_t)NEDGE * 4);
  int* bsum   = (int*)alloc(256 * 4);

  const int TT = (N_ATOMS + 63) / 64;  // 782 transpose tiles

  // input transposes (coalesced d-loads for the register GEMMs)
  transposeT<144><<<TT, 256, 0, stream>>>(angle, angleT);
  transposeT<12><<<TT, 256, 0, stream>>>(bond, bondT);

  // weights -> fp16
  cvtW<<<dim3(2, 256), 256, 0, stream>>>(Wl_b1, Wr_b1, Wb1c, 480);
  cvtW<<<dim3(5, 256), 256, 0, stream>>>(Wl_a1, Wr_a1, Wa1c, 1152);
  cvtW_small<<<512, 256, 0, stream>>>(Wl_b, Wr_b, Wl_a, Wr_a, Wsm);

  // CSR build
  hipMemsetAsync(deg, 0, (size_t)2 * N_ATOMS * 4, stream);
  k_count<<<(NEDGE + 255) / 256, 256, 0, stream>>>(nbr, deg);
  k_scan1<<<NBLK, 256, 0, stream>>>(deg, rowptr, bsum);
  k_scan2<<<1, 256, 0, stream>>>(bsum);
  k_scan3<<<NBLK, 256, 0, stream>>>(rowptr, bsum);
  k_fill<<<(NEDGE + 255) / 256, 256, 0, stream>>>(nbr, rowptr, cursor, eidx);

  const int GG = (N_ATOMS + 127) / 128;  // 391
  const int AG = N_ATOMS / 16;           // 3125

  // layer 1 (register GEMM, GBF in-register; project-then-aggregate)
  gemm1_reg<2, 1152><<<dim3(GG, 2), 256, 0, stream>>>(angleT, Wa1c, Pa, Qa, N_ATOMS);
  gemm1_reg<1, 480><<<dim3(GG, 2), 256, 0, stream>>>(bondT, Wb1c, Pb, Qb, N_ATOMS);
  gather_fin1<<<dim3(AG, 2), 256, 0, stream>>>(Pb, Qb, Pa, Qa, rowptr, eidx,
                                               b_b1, b_a1, axbA, axaA);

  // layers 2-3 (aggregate-then-project, ping-pong A -> B -> A)
  gather_mean<<<dim3(AG, 2), 256, 0, stream>>>(axbA, axaA, rowptr, eidx);
  gemmL_reg<<<dim3(GG, 2), 256, 0, stream>>>(axbA, axaA, axbB, axaB, Wsm, b_b, b_a,
                                             0, N_ATOMS);
  gather_mean<<<dim3(AG, 2), 256, 0, stream>>>(axbB, axaB, rowptr, eidx);
  gemmL_reg<<<dim3(GG, 2), 256, 0, stream>>>(axbB, axaB, axbA, axaA, Wsm, b_b, b_a,
                                             1, N_ATOMS);

  // head
  head_kernel<<<NCRYS, 256, 0, stream>>>(axbA, axaA, crys, W_mlp, b_mlp, W_fc, b_fc,
                                         (float*)d_out);
}

// Round 8
// 451.792 us; speedup vs baseline: 1.0603x; 1.0603x over previous
//
#include <hip/hip_runtime.h>

typedef _Float16 f16;
typedef _Float16 f16x8 __attribute__((ext_vector_type(8)));
typedef float f32x4 __attribute__((ext_vector_type(4)));

#define N_ATOMS 50000
#define NEIGH   12
#define NEDGE   (N_ATOMS * NEIGH)
#define NCRYS   500
#define NBLK    196  // ceil(50000/256)

// ---------------- layer-1 GEMM: [P|Q] = GBF(A) @ Wcat^T ----------------
// 512 thr = 8 waves (2 wr x 4 wc). BM=128 rows, BN=256 cols (cols<128 -> P, else Q).
// A (GBF) computed ONCE per block into LDS via exp-recurrence; B per-lane registers
// (16 lanes of a wave share each 64-B W line -> fully-used L2 traffic).
// MODE 1: bond fp32 [N][12], K=480 (40 filters, gamma=8/40), two 4-runs per 8 (underflow-safe).
// MODE 2: angle fp32 [N][144], K=1152 (8 filters, gamma=2/8), one 8-run.
template <int MODE, int K>
__global__ __launch_bounds__(512) void gemm1(
    const float* __restrict__ Asrc, const f16* __restrict__ Wcat,
    f16* __restrict__ P, f16* __restrict__ Q, int n) {
  __shared__ __align__(16) f16 As[2][4][128][8];  // 16 KB
  const int tid = threadIdx.x;
  const int lane = tid & 63;
  const int wid = tid >> 6;
  const int wr = wid >> 2;  // 0..1
  const int wc = wid & 3;   // 0..3
  const int row0 = blockIdx.x * 128;
  const int r16 = lane & 15;
  const int kb = lane >> 4;

  // A-compute mapping: thread -> (row, kb); jn-fast for coalesced source reads
  const int sAkb = tid & 3;
  const int sArow = tid >> 2;  // 0..127
  int arow = row0 + sArow;
  if (arow >= n) arow = n - 1;

  const f16* wb[4];
#pragma unroll
  for (int q = 0; q < 4; ++q)
    wb[q] = Wcat + (size_t)(wc * 64 + q * 16 + r16) * K + kb * 8;

  constexpr float G2I = (MODE == 1) ? 25.0f : 16.0f;
  constexpr float DLT = (MODE == 1) ? (8.0f / 39.0f) : (2.0f / 7.0f);
  constexpr float C1 = 2.0f * G2I * DLT;
  constexpr float C2 = G2I * DLT * DLT;
  const float S = __expf(-2.0f * C2);
  constexpr int RUN = (MODE == 1) ? 4 : 8;  // recurrence run length

  f32x4 acc[4][4];
#pragma unroll
  for (int m = 0; m < 4; ++m)
#pragma unroll
    for (int q = 0; q < 4; ++q) acc[m][q] = (f32x4)0.f;

  auto stageA = [&](int buf, int t) {
    int kg0 = t * 32 + sAkb * 8;
    int jn, kk0;
    if constexpr (MODE == 1) {
      jn = kg0 / 40;
      kk0 = kg0 - jn * 40;
    } else {
      jn = kg0 >> 3;
      kk0 = 0;
    }
    float d = Asrc[(size_t)arow * (MODE == 1 ? 12 : 144) + jn];
    f16 v[8];
#pragma unroll
    for (int h = 0; h < 8 / RUN; ++h) {
      float f0 = (float)(kk0 + h * RUN) * DLT + (MODE == 2 ? -1.0f : 0.0f);
      float u = d - f0;
      float g = __expf(-G2I * u * u);
      float ratio = __expf(C1 * u - C2);
      v[h * RUN] = (f16)g;
#pragma unroll
      for (int j = 1; j < RUN; ++j) {
        g *= ratio;
        ratio *= S;
        v[h * RUN + j] = (f16)g;
      }
    }
    *(f16x8*)&As[buf][sAkb][sArow][0] = *(const f16x8*)v;
  };

  constexpr int NT = K / 32;
  f16x8 bcur[4], bnxt[4];
  stageA(0, 0);
#pragma unroll
  for (int q = 0; q < 4; ++q) bcur[q] = *(const f16x8*)(wb[q]);
  __syncthreads();
  int buf = 0;
  for (int t = 0; t < NT; ++t) {
    if (t + 1 < NT) {
      stageA(buf ^ 1, t + 1);
#pragma unroll
      for (int q = 0; q < 4; ++q) bnxt[q] = *(const f16x8*)(wb[q] + (t + 1) * 32);
    }
    f16x8 a[4];
#pragma unroll
    for (int m = 0; m < 4; ++m)
      a[m] = *(const f16x8*)&As[buf][kb][wr * 64 + m * 16 + r16][0];
#pragma unroll
    for (int m = 0; m < 4; ++m)
#pragma unroll
      for (int q = 0; q < 4; ++q)
        acc[m][q] =
            __builtin_amdgcn_mfma_f32_16x16x32_f16(a[m], bcur[q], acc[m][q], 0, 0, 0);
    __syncthreads();
#pragma unroll
    for (int q = 0; q < 4; ++q) bcur[q] = bnxt[q];
    buf ^= 1;
  }

  const int crow = (lane >> 4) * 4;
  const int ccol = lane & 15;
  f16* outp = (wc < 2) ? P : Q;
  const int cbase = (wc & 1) * 64;
#pragma unroll
  for (int m = 0; m < 4; ++m) {
#pragma unroll
    for (int r = 0; r < 4; ++r) {
      int row = row0 + wr * 64 + m * 16 + crow + r;
      if (row < n) {
#pragma unroll
        for (int q = 0; q < 4; ++q)
          outp[(size_t)row * 128 + cbase + q * 16 + ccol] = (f16)acc[m][q][r];
      }
    }
  }
}

// ---------------- layers 2-3 register GEMM: dst.x = relu([agg|x]@W^T + b) ----
// Reads src[N][256] rows of its OWN tile only; writes x-half of dst (ping-pong:
// avoids the intra-block read-x/write-x race).
__global__ __launch_bounds__(256) void gemmL_reg(
    const f16* __restrict__ srcB, const f16* __restrict__ srcA,
    f16* __restrict__ dstB, f16* __restrict__ dstA, const f16* __restrict__ Wall,
    const float* __restrict__ bb, const float* __restrict__ ba, int lidx, int n) {
  const int path = blockIdx.y;
  const f16* src = path ? srcA : srcB;
  f16* dst = path ? dstA : dstB;
  const f16* W = Wall + (size_t)(path * 2 + lidx) * 32768;
  const float* bias = (path ? ba : bb) + lidx * 128;

  const int lane = threadIdx.x & 63;
  const int wid = threadIdx.x >> 6;
  const int wr = wid & 1;
  const int wc = wid >> 1;
  const int row0 = blockIdx.x * 128;
  const int r16 = lane & 15;
  const int kb = lane >> 4;

  int rm[4];
#pragma unroll
  for (int m = 0; m < 4; ++m) {
    int r = row0 + wr * 64 + m * 16 + r16;
    rm[m] = (r < n) ? r : (n - 1);
  }
  const f16* wb[4];
#pragma unroll
  for (int q = 0; q < 4; ++q)
    wb[q] = W + (size_t)(wc * 64 + q * 16 + r16) * 256 + kb * 8;

  f32x4 acc[4][4];
#pragma unroll
  for (int m = 0; m < 4; ++m)
#pragma unroll
    for (int q = 0; q < 4; ++q) acc[m][q] = (f32x4)0.f;

#pragma unroll
  for (int t = 0; t < 8; ++t) {
    f16x8 a[4], b[4];
#pragma unroll
    for (int m = 0; m < 4; ++m)
      a[m] = *(const f16x8*)&src[(size_t)rm[m] * 256 + t * 32 + kb * 8];
#pragma unroll
    for (int q = 0; q < 4; ++q) b[q] = *(const f16x8*)(wb[q] + t * 32);
#pragma unroll
    for (int m = 0; m < 4; ++m)
#pragma unroll
      for (int q = 0; q < 4; ++q)
        acc[m][q] =
            __builtin_amdgcn_mfma_f32_16x16x32_f16(a[m], b[q], acc[m][q], 0, 0, 0);
  }

  const int crow = (lane >> 4) * 4;
  const int ccol = lane & 15;
#pragma unroll
  for (int m = 0; m < 4; ++m) {
#pragma unroll
    for (int r = 0; r < 4; ++r) {
      int row = row0 + wr * 64 + m * 16 + crow + r;
      if (row < n) {
#pragma unroll
        for (int q = 0; q < 4; ++q) {
          int col = wc * 64 + q * 16 + ccol;
          float v = acc[m][q][r] + bias[col];
          dst[(size_t)row * 256 + 128 + col] = (f16)fmaxf(v, 0.0f);
        }
      }
    }
  }
}

// ---------------- weight conversion ----------------
__global__ void cvtW(const float* __restrict__ Wl, const float* __restrict__ Wr,
                     f16* __restrict__ outp, int K) {
  int c = blockIdx.y;
  int k = blockIdx.x * 256 + threadIdx.x;
  if (k < K)
    outp[(size_t)c * K + k] =
        (f16)((c < 128) ? Wl[(size_t)c * K + k] : Wr[(size_t)(c - 128) * K + k]);
}

__global__ void cvtW_small(const float* __restrict__ Wl_b, const float* __restrict__ Wr_b,
                           const float* __restrict__ Wl_a, const float* __restrict__ Wr_a,
                           f16* __restrict__ outp) {
  int idx = blockIdx.x * 256 + threadIdx.x;  // 4*128*256
  int l = idx >> 15;
  int c = (idx >> 8) & 127;
  int k = idx & 255;
  const float* Wl = (l < 2) ? Wl_b + (size_t)l * 16384 : Wl_a + (size_t)(l - 2) * 16384;
  const float* Wr = (l < 2) ? Wr_b + (size_t)l * 16384 : Wr_a + (size_t)(l - 2) * 16384;
  float v = (k < 128) ? Wl[(size_t)c * 128 + k] : Wr[(size_t)c * 128 + (k - 128)];
  outp[idx] = (f16)v;
}

// ---------------- CSR build ----------------
__global__ void k_count(const int* __restrict__ nbr, int* __restrict__ deg) {
  int e = blockIdx.x * 256 + threadIdx.x;
  if (e < NEDGE) atomicAdd(&deg[nbr[e]], 1);
}
__global__ void k_scan1(const int* __restrict__ deg, int* __restrict__ rowptr,
                        int* __restrict__ bsum) {
  __shared__ int s[256];
  int t = threadIdx.x, i = blockIdx.x * 256 + t;
  int v = (i < N_ATOMS) ? deg[i] : 0;
  s[t] = v;
  __syncthreads();
  for (int off = 1; off < 256; off <<= 1) {
    int x = (t >= off) ? s[t - off] : 0;
    __syncthreads();
    s[t] += x;
    __syncthreads();
  }
  if (i < N_ATOMS) rowptr[i] = s[t] - v;
  if (t == 255) bsum[blockIdx.x] = s[255];
}
__global__ void k_scan2(int* __restrict__ bsum) {
  __shared__ int s[256];
  int t = threadIdx.x;
  int v = (t < NBLK) ? bsum[t] : 0;
  s[t] = v;
  __syncthreads();
  for (int off = 1; off < 256; off <<= 1) {
    int x = (t >= off) ? s[t - off] : 0;
    __syncthreads();
    s[t] += x;
    __syncthreads();
  }
  if (t < NBLK) bsum[t] = s[t] - v;
}
__global__ void k_scan3(int* __restrict__ rowptr, const int* __restrict__ bsum) {
  int i = blockIdx.x * 256 + threadIdx.x;
  if (i < N_ATOMS) rowptr[i] += bsum[blockIdx.x];
  if (i == 0) rowptr[N_ATOMS] = NEDGE;
}
__global__ void k_fill(const int* __restrict__ nbr, const int* __restrict__ rowptr,
                       int* __restrict__ cursor, int* __restrict__ eidx) {
  int e = blockIdx.x * 256 + threadIdx.x;
  if (e < NEDGE) {
    int dst = nbr[e];
    int pos = rowptr[dst] + atomicAdd(&cursor[dst], 1);
    eidx[pos] = e / NEIGH;
  }
}

// ---------------- layer-1 finalize: x = relu(mean_j P[src_j] + b + Q) ----------------
// 16 thr/atom, f16x8 per edge; 8-deep batched loads for latency hiding.
__global__ __launch_bounds__(256) void gather_fin1(
    const f16* __restrict__ Pb, const f16* __restrict__ Qb,
    const f16* __restrict__ Pa, const f16* __restrict__ Qa,
    const int* __restrict__ rowptr, const int* __restrict__ eidx,
    const float* __restrict__ bias_b, const float* __restrict__ bias_a,
    f16* __restrict__ axb, f16* __restrict__ axa) {
  const int path = blockIdx.y;
  const f16* P = path ? Pa : Pb;
  const f16* Q = path ? Qa : Qb;
  const float* bias = path ? bias_a : bias_b;
  f16* ax = path ? axa : axb;
  const int t = threadIdx.x;
  const int a = blockIdx.x * 16 + (t >> 4);
  const int g = (t & 15) * 8;
  const int s0 = rowptr[a], s1 = rowptr[a + 1];
  float acc[8];
#pragma unroll
  for (int u = 0; u < 8; ++u) acc[u] = 0.f;
  int j = s0;
  for (; j + 8 <= s1; j += 8) {
    int e[8];
#pragma unroll
    for (int u = 0; u < 8; ++u) e[u] = eidx[j + u];
    f16x8 v[8];
#pragma unroll
    for (int u = 0; u < 8; ++u) v[u] = *(const f16x8*)&P[(size_t)e[u] * 128 + g];
#pragma unroll
    for (int u = 0; u < 8; ++u)
#pragma unroll
      for (int c = 0; c < 8; ++c) acc[c] += (float)v[u][c];
  }
  for (; j + 4 <= s1; j += 4) {
    int e0 = eidx[j], e1 = eidx[j + 1], e2 = eidx[j + 2], e3 = eidx[j + 3];
    f16x8 v0 = *(const f16x8*)&P[(size_t)e0 * 128 + g];
    f16x8 v1 = *(const f16x8*)&P[(size_t)e1 * 128 + g];
    f16x8 v2 = *(const f16x8*)&P[(size_t)e2 * 128 + g];
    f16x8 v3 = *(const f16x8*)&P[(size_t)e3 * 128 + g];
#pragma unroll
    for (int c = 0; c < 8; ++c)
      acc[c] += ((float)v0[c] + (float)v1[c]) + ((float)v2[c] + (float)v3[c]);
  }
  for (; j < s1; ++j) {
    f16x8 v = *(const f16x8*)&P[(size_t)eidx[j] * 128 + g];
#pragma unroll
    for (int c = 0; c < 8; ++c) acc[c] += (float)v[c];
  }
  f16x8 q = *(const f16x8*)&Q[(size_t)a * 128 + g];
  float inv = 1.0f / fmaxf((float)(s1 - s0), 1.0f);
  f16 outv[8];
#pragma unroll
  for (int u = 0; u < 8; ++u) {
    float v = acc[u] * inv + bias[g + u] + (float)q[u];
    outv[u] = (f16)fmaxf(v, 0.0f);
  }
  *(f16x8*)&ax[(size_t)a * 256 + 128 + g] = *(const f16x8*)outv;
}

// ---------------- layers 2-3 aggregation: agg half <- mean_j x[src_j] ----------------
__global__ __launch_bounds__(256) void gather_mean(
    f16* __restrict__ axb, f16* __restrict__ axa,
    const int* __restrict__ rowptr, const int* __restrict__ eidx) {
  f16* ax = blockIdx.y ? axa : axb;
  const int t = threadIdx.x;
  const int a = blockIdx.x * 16 + (t >> 4);
  const int g = (t & 15) * 8;
  const int s0 = rowptr[a], s1 = rowptr[a + 1];
  float acc[8];
#pragma unroll
  for (int u = 0; u < 8; ++u) acc[u] = 0.f;
  int j = s0;
  for (; j + 8 <= s1; j += 8) {
    int e[8];
#pragma unroll
    for (int u = 0; u < 8; ++u) e[u] = eidx[j + u];
    f16x8 v[8];
#pragma unroll
    for (int u = 0; u < 8; ++u)
      v[u] = *(const f16x8*)&ax[(size_t)e[u] * 256 + 128 + g];
#pragma unroll
    for (int u = 0; u < 8; ++u)
#pragma unroll
      for (int c = 0; c < 8; ++c) acc[c] += (float)v[u][c];
  }
  for (; j + 4 <= s1; j += 4) {
    int e0 = eidx[j], e1 = eidx[j + 1], e2 = eidx[j + 2], e3 = eidx[j + 3];
    f16x8 v0 = *(const f16x8*)&ax[(size_t)e0 * 256 + 128 + g];
    f16x8 v1 = *(const f16x8*)&ax[(size_t)e1 * 256 + 128 + g];
    f16x8 v2 = *(const f16x8*)&ax[(size_t)e2 * 256 + 128 + g];
    f16x8 v3 = *(const f16x8*)&ax[(size_t)e3 * 256 + 128 + g];
#pragma unroll
    for (int c = 0; c < 8; ++c)
      acc[c] += ((float)v0[c] + (float)v1[c]) + ((float)v2[c] + (float)v3[c]);
  }
  for (; j < s1; ++j) {
    f16x8 v = *(const f16x8*)&ax[(size_t)eidx[j] * 256 + 128 + g];
#pragma unroll
    for (int c = 0; c < 8; ++c) acc[c] += (float)v[c];
  }
  float inv = 1.0f / fmaxf((float)(s1 - s0), 1.0f);
  f16 outv[8];
#pragma unroll
  for (int u = 0; u < 8; ++u) outv[u] = (f16)(acc[u] * inv);
  *(f16x8*)&ax[(size_t)a * 256 + g] = *(const f16x8*)outv;
}

// ---------------- head: pool -> mlp -> mlp -> fc ----------------
__global__ __launch_bounds__(256) void head_kernel(
    const f16* __restrict__ axb, const f16* __restrict__ axa,
    const int* __restrict__ crys, const float* __restrict__ W_mlp,
    const float* __restrict__ b_mlp, const float* __restrict__ W_fc,
    const float* __restrict__ b_fc, float* __restrict__ outp) {
  __shared__ float sh0[256], sh1[256];
  const int cry = blockIdx.x, c = threadIdx.x;
  const int s = crys[2 * cry], e = crys[2 * cry + 1];
  const f16* src = (c < 128) ? axb : axa;
  const int ch = c & 127;
  float sum = 0.f;
  for (int r = s; r < e; ++r) sum += (float)src[(size_t)r * 256 + 128 + ch];
  sh0[c] = sum / fmaxf((float)(e - s), 1.0f);
  __syncthreads();
  {
    const float* wrow = W_mlp + (size_t)c * 256;
    float s2 = b_mlp[c];
#pragma unroll 8
    for (int k = 0; k < 256; k += 4) {
      float4 w = *(const float4*)&wrow[k];
      s2 += sh0[k] * w.x + sh0[k + 1] * w.y + sh0[k + 2] * w.z + sh0[k + 3] * w.w;
    }
    sh1[c] = s2;
  }
  __syncthreads();
  {
    const float* wrow = W_mlp + 65536 + (size_t)c * 256;
    float s2 = b_mlp[256 + c];
#pragma unroll 8
    for (int k = 0; k < 256; k += 4) {
      float4 w = *(const float4*)&wrow[k];
      s2 += sh1[k] * w.x + sh1[k + 1] * w.y + sh1[k + 2] * w.z + sh1[k + 3] * w.w;
    }
    sh0[c] = s2;
  }
  __syncthreads();
  if (c < 2) {
    const float* wrow = W_fc + c * 256;
    float s2 = b_fc[c];
    for (int k = 0; k < 256; ++k) s2 += sh0[k] * wrow[k];
    outp[cry * 2 + c] = s2;
  }
}

extern "C" void kernel_launch(void* const* d_in, const int* in_sizes, int n_in,
                              void* d_out, int out_size, void* d_ws, size_t ws_size,
                              hipStream_t stream) {
  const float* bond  = (const float*)d_in[0];
  const float* angle = (const float*)d_in[1];
  const int*   nbr   = (const int*)d_in[3];
  const int*   crys  = (const int*)d_in[4];
  const float* Wl_b1 = (const float*)d_in[5];
  const float* Wr_b1 = (const float*)d_in[6];
  const float* b_b1  = (const float*)d_in[7];
  const float* Wl_a1 = (const float*)d_in[8];
  const float* Wr_a1 = (const float*)d_in[9];
  const float* b_a1  = (const float*)d_in[10];
  const float* Wl_b  = (const float*)d_in[11];
  const float* Wr_b  = (const float*)d_in[12];
  const float* b_b   = (const float*)d_in[13];
  const float* Wl_a  = (const float*)d_in[14];
  const float* Wr_a  = (const float*)d_in[15];
  const float* b_a   = (const float*)d_in[16];
  const float* W_mlp = (const float*)d_in[17];
  const float* b_mlp = (const float*)d_in[18];
  const float* W_fc  = (const float*)d_in[19];
  const float* b_fc  = (const float*)d_in[20];

  char* w = (char*)d_ws;
  auto alloc = [&](size_t bytes) {
    void* p = (void*)w;
    w += (bytes + 255) & ~(size_t)255;
    return p;
  };
  // ping-pong activation buffers; layer-1 P/Q alias the B buffers
  f16* axbA = (f16*)alloc((size_t)N_ATOMS * 256 * 2);
  f16* axaA = (f16*)alloc((size_t)N_ATOMS * 256 * 2);
  f16* axbB = (f16*)alloc((size_t)N_ATOMS * 256 * 2);
  f16* axaB = (f16*)alloc((size_t)N_ATOMS * 256 * 2);
  f16* Pb = axbB;
  f16* Qb = axbB + (size_t)N_ATOMS * 128;
  f16* Pa = axaB;
  f16* Qa = axaB + (size_t)N_ATOMS * 128;
  f16* Wb1c = (f16*)alloc((size_t)256 * 480 * 2);
  f16* Wa1c = (f16*)alloc((size_t)256 * 1152 * 2);
  f16* Wsm  = (f16*)alloc((size_t)4 * 128 * 256 * 2);
  // deg+cursor as ONE contiguous block: the single memset must cover BOTH
  // (0xAA re-poison between timed replays otherwise leaves cursor garbage).
  int* deg    = (int*)alloc((size_t)2 * N_ATOMS * 4);
  int* cursor = deg + N_ATOMS;
  int* rowptr = (int*)alloc((size_t)(N_ATOMS + 1) * 4);
  int* eidx   = (int*)alloc((size_t)NEDGE * 4);
  int* bsum   = (int*)alloc(256 * 4);

  // weights -> fp16
  cvtW<<<dim3(2, 256), 256, 0, stream>>>(Wl_b1, Wr_b1, Wb1c, 480);
  cvtW<<<dim3(5, 256), 256, 0, stream>>>(Wl_a1, Wr_a1, Wa1c, 1152);
  cvtW_small<<<512, 256, 0, stream>>>(Wl_b, Wr_b, Wl_a, Wr_a, Wsm);

  // CSR build
  hipMemsetAsync(deg, 0, (size_t)2 * N_ATOMS * 4, stream);
  k_count<<<(NEDGE + 255) / 256, 256, 0, stream>>>(nbr, deg);
  k_scan1<<<NBLK, 256, 0, stream>>>(deg, rowptr, bsum);
  k_scan2<<<1, 256, 0, stream>>>(bsum);
  k_scan3<<<NBLK, 256, 0, stream>>>(rowptr, bsum);
  k_fill<<<(NEDGE + 255) / 256, 256, 0, stream>>>(nbr, rowptr, cursor, eidx);

  const int GG = (N_ATOMS + 127) / 128;  // 391
  const int AG = N_ATOMS / 16;           // 3125

  // layer 1: GBF fused (exp-recurrence, LDS-shared A, reg-B), project-then-aggregate
  gemm1<2, 1152><<<GG, 512, 0, stream>>>(angle, Wa1c, Pa, Qa, N_ATOMS);
  gemm1<1, 480><<<GG, 512, 0, stream>>>(bond, Wb1c, Pb, Qb, N_ATOMS);
  gather_fin1<<<dim3(AG, 2), 256, 0, stream>>>(Pb, Qb, Pa, Qa, rowptr, eidx,
                                               b_b1, b_a1, axbA, axaA);

  // layers 2-3 (aggregate-then-project, ping-pong A -> B -> A)
  gather_mean<<<dim3(AG, 2), 256, 0, stream>>>(axbA, axaA, rowptr, eidx);
  gemmL_reg<<<dim3(GG, 2), 256, 0, stream>>>(axbA, axaA, axbB, axaB, Wsm, b_b, b_a,
                                             0, N_ATOMS);
  gather_mean<<<dim3(AG, 2), 256, 0, stream>>>(axbB, axaB, rowptr, eidx);
  gemmL_reg<<<dim3(GG, 2), 256, 0, stream>>>(axbB, axaB, axbA, axaA, Wsm, b_b, b_a,
                                             1, N_ATOMS);

  // head
  head_kernel<<<NCRYS, 256, 0, stream>>>(axbA, axaA, crys, W_mlp, b_mlp, W_fc, b_fc,
                                         (float*)d_out);
}